// Round 4
// baseline (512.539 us; speedup 1.0000x reference)
//
#include <hip/hip_runtime.h>

// SimpleLSTM: 2-layer LSTM (B=512,T=256,F=64,U=128) + Dense(1,relu).
// Persistent-RNN: fp16 weights pinned in VGPRs via per-fragment in-loop
// asm value-pins ("+v" redefines each iter -> reload-from-memory illegal).
// 256 WGs x 512 thr, 2 batch rows/WG, single barrier/step.
// A-frag LDS loads exec-masked to the 2 real rows. log2e folded into weights.

#define T_STEPS 256
#define BATCH   512
#define NU      128
#define FDIM    64

typedef _Float16 h8 __attribute__((ext_vector_type(8)));
typedef _Float16 h4 __attribute__((ext_vector_type(4)));
typedef float    f4 __attribute__((ext_vector_type(4)));

#define LOG2E    1.4426950408889634f
#define TWOLOG2E 2.8853900817779268f

// Force VALUE residency: empty asm that "redefines" x each call. A reload
// from memory cannot reproduce the asm's (identity) output per the compiler's
// model, so the register chain must stay live across the whole time loop.
#define PINV(x) asm volatile("" : "+v"(x))

#if __has_builtin(__builtin_amdgcn_exp2f)
#define EXP2F(x) __builtin_amdgcn_exp2f(x)
#else
#define EXP2F(x) exp2f(x)
#endif
#if __has_builtin(__builtin_amdgcn_rcpf)
#define RCPF(x) __builtin_amdgcn_rcpf(x)
#else
#define RCPF(x) (1.0f / (x))
#endif

__device__ __forceinline__ float sigm2(float s) {   // s = z*log2e
    return RCPF(1.0f + EXP2F(-s));
}
__device__ __forceinline__ float tanh2(float t) {   // t = 2*z*log2e
    return 1.0f - 2.0f * RCPF(1.0f + EXP2F(t));
}

// ---- weight prep: transpose to col-major [col][k], cast fp16, fold log2e ----
__global__ void prep_weights(const float* __restrict__ W1, const float* __restrict__ U1,
                             const float* __restrict__ b1, const float* __restrict__ W2,
                             const float* __restrict__ U2, const float* __restrict__ b2,
                             _Float16* __restrict__ Wp1, _Float16* __restrict__ Up1,
                             _Float16* __restrict__ Wp2, _Float16* __restrict__ Up2,
                             float* __restrict__ bp1, float* __restrict__ bp2) {
    int i = blockIdx.x * 256 + threadIdx.x;
    if (i < 32768) {                       // Wp1 [512][64] from W1 [64][512]
        int col = i >> 6, k = i & 63;
        float sc = ((col >> 7) == 2) ? TWOLOG2E : LOG2E;
        Wp1[i] = (_Float16)(W1[k * 512 + col] * sc);
    } else if (i < 32768 + 65536) {        // Up1 [512][128] from U1 [128][512]
        int j = i - 32768; int col = j >> 7, k = j & 127;
        float sc = ((col >> 7) == 2) ? TWOLOG2E : LOG2E;
        Up1[j] = (_Float16)(U1[k * 512 + col] * sc);
    } else if (i < 32768 + 131072) {       // Wp2 [512][128] from W2 [128][512]
        int j = i - 98304; int col = j >> 7, k = j & 127;
        float sc = ((col >> 7) == 2) ? TWOLOG2E : LOG2E;
        Wp2[j] = (_Float16)(W2[k * 512 + col] * sc);
    } else if (i < 32768 + 196608) {       // Up2 [512][128] from U2 [128][512]
        int j = i - 163840; int col = j >> 7, k = j & 127;
        float sc = ((col >> 7) == 2) ? TWOLOG2E : LOG2E;
        Up2[j] = (_Float16)(U2[k * 512 + col] * sc);
    } else if (i < 32768 + 196608 + 1024) {
        int j = i - 229376;
        if (j < 512) {
            float sc = ((j >> 7) == 2) ? TWOLOG2E : LOG2E;
            bp1[j] = b1[j] * sc;
        } else {
            int col = j - 512;
            float sc = ((col >> 7) == 2) ? TWOLOG2E : LOG2E;
            bp2[col] = b2[col] * sc;
        }
    }
}

// ---- LSTM layer kernel ----
// IS_A: input = x (f32 [B,T,F]), writes hs fp16 [T,B,U].
// !IS_A: input = hs (fp16 [T,B,U]), fused dense at end.
template <bool IS_A>
__global__ __launch_bounds__(512, 2) void lstm_layer(
    const float* __restrict__ xA, const _Float16* __restrict__ xB,
    const _Float16* __restrict__ Wp,   // [512][KX] col-major, scaled fp16
    const _Float16* __restrict__ Up,   // [512][128]
    const float* __restrict__ bp,      // [512] scaled
    _Float16* __restrict__ hs_out,
    const float* __restrict__ Wd, const float* __restrict__ bd,
    float* __restrict__ dout) {
    constexpr int KX  = IS_A ? 64 : 128;
    constexpr int KXS = KX / 32;
    constexpr int PX  = IS_A ? 72 : 136;  // halfs; rows 16B-aligned
    constexpr int PH  = 136;
    constexpr int H0  = 0;                // h buffers: 2 rows x PH, double
    constexpr int H1  = 2 * PH;
    constexpr int X0  = 4 * PH;           // x buffers: 2 rows x PX, double
    constexpr int X1  = X0 + 2 * PX;
    constexpr int SMH = X1 + 2 * PX;

    __shared__ __align__(16) _Float16 sm[SMH];

    const int tid  = threadIdx.x;
    const int lane = tid & 63;
    const int wv   = tid >> 6;       // 0..7, each owns 16 units x 4 gates
    const int m    = lane & 15;
    const int kc   = lane >> 4;      // quad 0..3
    const int u0   = wv * 16;
    const int b0   = blockIdx.x * 2;

    // zero LDS (h0 = 0 for t=0)
    for (int i = tid; i < SMH; i += 512) sm[i] = (_Float16)0.0f;

    // weight fragments -> registers (B-frag: B[k=kc*8+j][n=m], col-major source)
    h8 wf[4][KXS], uf[4][4];
#pragma unroll
    for (int g = 0; g < 4; g++) {
#pragma unroll
        for (int ks = 0; ks < KXS; ks++)
            wf[g][ks] = *(const h8*)&Wp[(g * 128 + u0 + m) * KX + ks * 32 + kc * 8];
#pragma unroll
        for (int ks = 0; ks < 4; ks++)
            uf[g][ks] = *(const h8*)&Up[(g * 128 + u0 + m) * 128 + ks * 32 + kc * 8];
    }
    float bias[4];
#pragma unroll
    for (int g = 0; g < 4; g++) bias[g] = bp[g * 128 + u0 + m];

    const bool stager = (wv == 4) && (lane >= 32);
    const int prow = (lane >> 4) - 2;   // 0..1 (stager lanes)
    const int pcol = lane & 15;

    __syncthreads();   // LDS zeroed

    // stage t=0 input into X0
    if (stager) {
        if constexpr (IS_A) {
            f4 v = *(const f4*)&xA[(size_t)((b0 + prow) * T_STEPS + 0) * FDIM + pcol * 4];
            h4 hv = {(_Float16)v.x, (_Float16)v.y, (_Float16)v.z, (_Float16)v.w};
            *(h4*)&sm[X0 + prow * PX + pcol * 4] = hv;
        } else {
            *(h8*)&sm[X0 + prow * PX + pcol * 8] =
                *(const h8*)&xB[(size_t)(0 * BATCH + b0 + prow) * NU + pcol * 8];
        }
    }
    __syncthreads();

    const h8 hzero = {(_Float16)0.f, (_Float16)0.f, (_Float16)0.f, (_Float16)0.f,
                      (_Float16)0.f, (_Float16)0.f, (_Float16)0.f, (_Float16)0.f};
    h8 xa[KXS], ha[4];
#pragma unroll
    for (int ks = 0; ks < KXS; ks++) xa[ks] = hzero;
#pragma unroll
    for (int ks = 0; ks < 4; ks++) ha[ks] = hzero;

    float c0 = 0.0f, c1 = 0.0f;

#pragma unroll 2
    for (int t = 0; t < T_STEPS; t++) {
        const int p = t & 1;

        // re-pin weight values every iteration: forbids any reload-from-memory
#pragma unroll
        for (int g = 0; g < 4; g++) {
#pragma unroll
            for (int ks = 0; ks < KXS; ks++) PINV(wf[g][ks]);
#pragma unroll
            for (int ks = 0; ks < 4; ks++) PINV(uf[g][ks]);
            PINV(bias[g]);
        }

        // next-step global prefetch (consumed at end of step)
        f4 xr; h8 xr8;
        const bool pf = stager && (t + 1 < T_STEPS);
        if (pf) {
            if constexpr (IS_A)
                xr = *(const f4*)&xA[(size_t)((b0 + prow) * T_STEPS + (t + 1)) * FDIM + pcol * 4];
            else
                xr8 = *(const h8*)&xB[(size_t)((t + 1) * BATCH + b0 + prow) * NU + pcol * 8];
        }

        // A-frags: only rows 0,1 are real; lanes m>=2 keep stale/zero regs
        if (m < 2) {
            const _Float16* xb = &sm[p ? X1 : X0];
            const _Float16* hb = &sm[p ? H1 : H0];
#pragma unroll
            for (int ks = 0; ks < KXS; ks++)
                xa[ks] = *(const h8*)&xb[m * PX + ks * 32 + kc * 8];
#pragma unroll
            for (int ks = 0; ks < 4; ks++)
                ha[ks] = *(const h8*)&hb[m * PH + ks * 32 + kc * 8];
        }

        f4 acc[4];
#pragma unroll
        for (int g = 0; g < 4; g++)
            acc[g] = (f4){bias[g], bias[g], bias[g], bias[g]};
#pragma unroll
        for (int ks = 0; ks < KXS; ks++)
#pragma unroll
            for (int g = 0; g < 4; g++)
                acc[g] = __builtin_amdgcn_mfma_f32_16x16x32_f16(xa[ks], wf[g][ks], acc[g], 0, 0, 0);
#pragma unroll
        for (int ks = 0; ks < 4; ks++)
#pragma unroll
            for (int g = 0; g < 4; g++)
                acc[g] = __builtin_amdgcn_mfma_f32_16x16x32_f16(ha[ks], uf[g][ks], acc[g], 0, 0, 0);

        // in-wave epilogue: rows 0,1 live in regs 0,1 of lanes 0..15
        if (lane < 16) {
            float gi0 = sigm2(acc[0][0]), gf0 = sigm2(acc[1][0]);
            float gg0 = tanh2(acc[2][0]), go0 = sigm2(acc[3][0]);
            c0 = gf0 * c0 + gi0 * gg0;
            float hv0 = go0 * tanh2(c0 * TWOLOG2E);
            float gi1 = sigm2(acc[0][1]), gf1 = sigm2(acc[1][1]);
            float gg1 = tanh2(acc[2][1]), go1 = sigm2(acc[3][1]);
            c1 = gf1 * c1 + gi1 * gg1;
            float hv1 = go1 * tanh2(c1 * TWOLOG2E);
            _Float16 h0v = (_Float16)hv0, h1v = (_Float16)hv1;
            _Float16* hbn = &sm[p ? H0 : H1];
            hbn[u0 + m] = h0v;
            hbn[PH + u0 + m] = h1v;
            if constexpr (IS_A) {
                hs_out[((size_t)t * BATCH + b0    ) * NU + u0 + m] = h0v;
                hs_out[((size_t)t * BATCH + b0 + 1) * NU + u0 + m] = h1v;
            }
        }
        if (pf) {
            _Float16* xbn = &sm[p ? X0 : X1];
            if constexpr (IS_A) {
                h4 hv4 = {(_Float16)xr.x, (_Float16)xr.y, (_Float16)xr.z, (_Float16)xr.w};
                *(h4*)&xbn[prow * PX + pcol * 4] = hv4;
            } else {
                *(h8*)&xbn[prow * PX + pcol * 8] = xr8;
            }
        }
        __syncthreads();
    }

    if constexpr (!IS_A) {
        // h(T): t=255 (p=1) wrote into H0
        if (wv == 0) {
            int rw = lane >> 5, u = lane & 31;
            float s = 0.0f;
#pragma unroll
            for (int j = 0; j < 4; j++) {
                int uum = u + j * 32;
                s += (float)sm[H0 + rw * PH + uum] * Wd[uum];
            }
            s += __shfl_xor(s, 16);
            s += __shfl_xor(s, 8);
            s += __shfl_xor(s, 4);
            s += __shfl_xor(s, 2);
            s += __shfl_xor(s, 1);
            if ((lane & 31) == 0) dout[b0 + rw] = fmaxf(s + bd[0], 0.0f);
        }
    }
}

extern "C" void kernel_launch(void* const* d_in, const int* in_sizes, int n_in,
                              void* d_out, int out_size, void* d_ws, size_t ws_size,
                              hipStream_t stream) {
    const float* x  = (const float*)d_in[0];
    const float* W1 = (const float*)d_in[1];
    const float* U1 = (const float*)d_in[2];
    const float* b1 = (const float*)d_in[3];
    const float* W2 = (const float*)d_in[4];
    const float* U2 = (const float*)d_in[5];
    const float* b2 = (const float*)d_in[6];
    const float* Wd = (const float*)d_in[7];
    const float* bd = (const float*)d_in[8];
    float* out = (float*)d_out;

    const size_t HS   = 33554432;              // hs fp16 [256][512][128]
    const size_t oWp1 = HS;
    const size_t oUp1 = oWp1 + 65536;
    const size_t oWp2 = oUp1 + 131072;
    const size_t oUp2 = oWp2 + 131072;
    const size_t oBp1 = oUp2 + 131072;
    const size_t oBp2 = oBp1 + 2048;
    const size_t need = oBp2 + 2048;           // 34,017,280
    if (ws_size < need) return;

    char* ws = (char*)d_ws;
    _Float16* hs  = (_Float16*)ws;
    _Float16* Wp1 = (_Float16*)(ws + oWp1);
    _Float16* Up1 = (_Float16*)(ws + oUp1);
    _Float16* Wp2 = (_Float16*)(ws + oWp2);
    _Float16* Up2 = (_Float16*)(ws + oUp2);
    float*    bp1 = (float*)(ws + oBp1);
    float*    bp2 = (float*)(ws + oBp2);

    prep_weights<<<900, 256, 0, stream>>>(W1, U1, b1, W2, U2, b2,
                                          Wp1, Up1, Wp2, Up2, bp1, bp2);
    lstm_layer<true><<<256, 512, 0, stream>>>(x, nullptr, Wp1, Up1, bp1,
                                              hs, nullptr, nullptr, nullptr);
    lstm_layer<false><<<256, 512, 0, stream>>>(nullptr, hs, Wp2, Up2, bp2,
                                               nullptr, Wd, bd, out);
}

// Round 5
// 456.899 us; speedup vs baseline: 1.1218x; 1.1218x over previous
//
#include <hip/hip_runtime.h>

// SimpleLSTM: 2-layer LSTM (B=512,T=256,F=64,U=128) + Dense(1,relu).
// Persistent-RNN: fp16 weights resident in VGPRs. Residency enforced by
//   (a) amdgpu_waves_per_eu(2,2): allocator budget 256 VGPRs, no occupancy
//       incentive to shrink below it (grid is 1 WG/CU anyway), and
//   (b) in-loop asm value-pins: remat-from-memory cannot reproduce the
//       pinned value, so the register chain must be carried.
// 256 WGs x 512 thr, 2 batch rows/WG, single barrier/step.
// x staged through an 8-slot LDS ring refilled 4 steps at a time (~2400 cyc
// of global-latency cover, one vmcnt wait per 4 steps).

#define T_STEPS 256
#define BATCH   512
#define NU      128
#define FDIM    64

typedef _Float16 h8 __attribute__((ext_vector_type(8)));
typedef _Float16 h4 __attribute__((ext_vector_type(4)));
typedef float    f4 __attribute__((ext_vector_type(4)));

#define LOG2E    1.4426950408889634f
#define TWOLOG2E 2.8853900817779268f

#define PINV(x) asm volatile("" : "+v"(x))

#if __has_builtin(__builtin_amdgcn_exp2f)
#define EXP2F(x) __builtin_amdgcn_exp2f(x)
#else
#define EXP2F(x) exp2f(x)
#endif
#if __has_builtin(__builtin_amdgcn_rcpf)
#define RCPF(x) __builtin_amdgcn_rcpf(x)
#else
#define RCPF(x) (1.0f / (x))
#endif

__device__ __forceinline__ float sigm2(float s) {   // s = z*log2e
    return RCPF(1.0f + EXP2F(-s));
}
__device__ __forceinline__ float tanh2(float t) {   // t = 2*z*log2e
    return 1.0f - 2.0f * RCPF(1.0f + EXP2F(t));
}

// ---- weight prep: transpose to col-major [col][k], cast fp16, fold log2e ----
__global__ void prep_weights(const float* __restrict__ W1, const float* __restrict__ U1,
                             const float* __restrict__ b1, const float* __restrict__ W2,
                             const float* __restrict__ U2, const float* __restrict__ b2,
                             _Float16* __restrict__ Wp1, _Float16* __restrict__ Up1,
                             _Float16* __restrict__ Wp2, _Float16* __restrict__ Up2,
                             float* __restrict__ bp1, float* __restrict__ bp2) {
    int i = blockIdx.x * 256 + threadIdx.x;
    if (i < 32768) {                       // Wp1 [512][64] from W1 [64][512]
        int col = i >> 6, k = i & 63;
        float sc = ((col >> 7) == 2) ? TWOLOG2E : LOG2E;
        Wp1[i] = (_Float16)(W1[k * 512 + col] * sc);
    } else if (i < 32768 + 65536) {        // Up1 [512][128] from U1 [128][512]
        int j = i - 32768; int col = j >> 7, k = j & 127;
        float sc = ((col >> 7) == 2) ? TWOLOG2E : LOG2E;
        Up1[j] = (_Float16)(U1[k * 512 + col] * sc);
    } else if (i < 32768 + 131072) {       // Wp2 [512][128] from W2 [128][512]
        int j = i - 98304; int col = j >> 7, k = j & 127;
        float sc = ((col >> 7) == 2) ? TWOLOG2E : LOG2E;
        Wp2[j] = (_Float16)(W2[k * 512 + col] * sc);
    } else if (i < 32768 + 196608) {       // Up2 [512][128] from U2 [128][512]
        int j = i - 163840; int col = j >> 7, k = j & 127;
        float sc = ((col >> 7) == 2) ? TWOLOG2E : LOG2E;
        Up2[j] = (_Float16)(U2[k * 512 + col] * sc);
    } else if (i < 32768 + 196608 + 1024) {
        int j = i - 229376;
        if (j < 512) {
            float sc = ((j >> 7) == 2) ? TWOLOG2E : LOG2E;
            bp1[j] = b1[j] * sc;
        } else {
            int col = j - 512;
            float sc = ((col >> 7) == 2) ? TWOLOG2E : LOG2E;
            bp2[col] = b2[col] * sc;
        }
    }
}

// ---- LSTM layer kernel ----
// IS_A: input = x (f32 [B,T,F]), writes hs fp16 [T,B,U].
// !IS_A: input = hs (fp16 [T,B,U]), fused dense at end.
template <bool IS_A>
__attribute__((amdgpu_waves_per_eu(2, 2)))
__global__ __launch_bounds__(512) void lstm_layer(
    const float* __restrict__ xA, const _Float16* __restrict__ xB,
    const _Float16* __restrict__ Wp,   // [512][KX] col-major, scaled fp16
    const _Float16* __restrict__ Up,   // [512][128]
    const float* __restrict__ bp,      // [512] scaled
    _Float16* __restrict__ hs_out,
    const float* __restrict__ Wd, const float* __restrict__ bd,
    float* __restrict__ dout) {
    constexpr int KX  = IS_A ? 64 : 128;
    constexpr int KXS = KX / 32;
    constexpr int PX  = IS_A ? 72 : 136;  // halfs; rows 16B-aligned
    constexpr int PH  = 136;
    constexpr int H0  = 0;                // h buffers: 2 rows x PH, double
    constexpr int H1  = 2 * PH;
    constexpr int XB  = 4 * PH;           // x ring: 8 slots x 2 rows x PX
    constexpr int XS  = 2 * PX;           // slot stride
    constexpr int SMH = XB + 8 * XS;

    __shared__ __align__(16) _Float16 sm[SMH];

    const int tid  = threadIdx.x;
    const int lane = tid & 63;
    const int wv   = tid >> 6;       // 0..7, each owns 16 units x 4 gates
    const int m    = lane & 15;
    const int kc   = lane >> 4;      // quad 0..3
    const int u0   = wv * 16;
    const int b0   = blockIdx.x * 2;

    // zero h region (h0 = 0 for t=0); x ring needs no zeroing
    for (int i = tid; i < XB; i += 512) sm[i] = (_Float16)0.0f;

    // weight fragments -> registers (B-frag: B[k=kc*8+j][n=m], col-major source)
    h8 wf[4][KXS], uf[4][4];
#pragma unroll
    for (int g = 0; g < 4; g++) {
#pragma unroll
        for (int ks = 0; ks < KXS; ks++)
            wf[g][ks] = *(const h8*)&Wp[(g * 128 + u0 + m) * KX + ks * 32 + kc * 8];
#pragma unroll
        for (int ks = 0; ks < 4; ks++)
            uf[g][ks] = *(const h8*)&Up[(g * 128 + u0 + m) * 128 + ks * 32 + kc * 8];
    }
    float bias[4];
#pragma unroll
    for (int g = 0; g < 4; g++) bias[g] = bp[g * 128 + u0 + m];

    const bool stager = (wv == 4) && (lane >= 32);
    const int prow = (lane >> 4) - 2;   // 0..1 (stager lanes)
    const int pcol = lane & 15;

    __syncthreads();   // LDS zeroed before stager writes

    // stager register buffer (4 slots)
    f4 rf[4]; h8 rh[4];
    if (stager) {
        // slots 0..3 <- steps 0..3
#pragma unroll
        for (int s = 0; s < 4; s++) {
            if constexpr (IS_A)
                rf[s] = *(const f4*)&xA[(size_t)((b0 + prow) * T_STEPS + s) * FDIM + pcol * 4];
            else
                rh[s] = *(const h8*)&xB[((size_t)s * BATCH + b0 + prow) * NU + pcol * 8];
        }
#pragma unroll
        for (int s = 0; s < 4; s++) {
            if constexpr (IS_A) {
                f4 v = rf[s];
                h4 hv = {(_Float16)v.x, (_Float16)v.y, (_Float16)v.z, (_Float16)v.w};
                *(h4*)&sm[XB + s * XS + prow * PX + pcol * 4] = hv;
            } else {
                *(h8*)&sm[XB + s * XS + prow * PX + pcol * 8] = rh[s];
            }
        }
        // in-flight: steps 4..7
#pragma unroll
        for (int s = 0; s < 4; s++) {
            if constexpr (IS_A)
                rf[s] = *(const f4*)&xA[(size_t)((b0 + prow) * T_STEPS + 4 + s) * FDIM + pcol * 4];
            else
                rh[s] = *(const h8*)&xB[((size_t)(4 + s) * BATCH + b0 + prow) * NU + pcol * 8];
        }
    }
    __syncthreads();

    const h8 hzero = {(_Float16)0.f, (_Float16)0.f, (_Float16)0.f, (_Float16)0.f,
                      (_Float16)0.f, (_Float16)0.f, (_Float16)0.f, (_Float16)0.f};
    h8 xa[KXS], ha[4];
#pragma unroll
    for (int ks = 0; ks < KXS; ks++) xa[ks] = hzero;
#pragma unroll
    for (int ks = 0; ks < 4; ks++) ha[ks] = hzero;

    float c0 = 0.0f, c1 = 0.0f;

#pragma unroll 4
    for (int t = 0; t < T_STEPS; t++) {
        const int p = t & 1;

        // pin weight values once per window: forbids remat across the loop
        if ((t & 3) == 0) {
#pragma unroll
            for (int g = 0; g < 4; g++) {
#pragma unroll
                for (int ks = 0; ks < KXS; ks++) PINV(wf[g][ks]);
#pragma unroll
                for (int ks = 0; ks < 4; ks++) PINV(uf[g][ks]);
                PINV(bias[g]);
            }
        }

        // A-frags: only rows 0,1 are real; lanes m>=2 keep zero regs
        if (m < 2) {
            const _Float16* xb = &sm[XB + (t & 7) * XS];
            const _Float16* hb = &sm[p ? H1 : H0];
#pragma unroll
            for (int ks = 0; ks < KXS; ks++)
                xa[ks] = *(const h8*)&xb[m * PX + ks * 32 + kc * 8];
#pragma unroll
            for (int ks = 0; ks < 4; ks++)
                ha[ks] = *(const h8*)&hb[m * PH + ks * 32 + kc * 8];
        }

        f4 acc[4];
#pragma unroll
        for (int g = 0; g < 4; g++)
            acc[g] = (f4){bias[g], bias[g], bias[g], bias[g]};
#pragma unroll
        for (int ks = 0; ks < KXS; ks++)
#pragma unroll
            for (int g = 0; g < 4; g++)
                acc[g] = __builtin_amdgcn_mfma_f32_16x16x32_f16(xa[ks], wf[g][ks], acc[g], 0, 0, 0);
#pragma unroll
        for (int ks = 0; ks < 4; ks++)
#pragma unroll
            for (int g = 0; g < 4; g++)
                acc[g] = __builtin_amdgcn_mfma_f32_16x16x32_f16(ha[ks], uf[g][ks], acc[g], 0, 0, 0);

        // in-wave epilogue: rows 0,1 live in regs 0,1 of lanes 0..15
        if (lane < 16) {
            float gi0 = sigm2(acc[0][0]), gf0 = sigm2(acc[1][0]);
            float gg0 = tanh2(acc[2][0]), go0 = sigm2(acc[3][0]);
            c0 = gf0 * c0 + gi0 * gg0;
            float hv0 = go0 * tanh2(c0 * TWOLOG2E);
            float gi1 = sigm2(acc[0][1]), gf1 = sigm2(acc[1][1]);
            float gg1 = tanh2(acc[2][1]), go1 = sigm2(acc[3][1]);
            c1 = gf1 * c1 + gi1 * gg1;
            float hv1 = go1 * tanh2(c1 * TWOLOG2E);
            _Float16 h0v = (_Float16)hv0, h1v = (_Float16)hv1;
            _Float16* hbn = &sm[p ? H0 : H1];
            hbn[u0 + m] = h0v;
            hbn[PH + u0 + m] = h1v;
            if constexpr (IS_A) {
                hs_out[((size_t)t * BATCH + b0    ) * NU + u0 + m] = h0v;
                hs_out[((size_t)t * BATCH + b0 + 1) * NU + u0 + m] = h1v;
            }
        }

        // window refill: at t%4==3 write steps t+1..t+4 into the OTHER ring
        // half (disjoint from any slot read before the next barrier), then
        // issue loads for t+5..t+8.
        if (stager && (t & 3) == 3 && t + 1 < T_STEPS) {
            const int wbase = XB + ((t + 1) & 7) * XS;
#pragma unroll
            for (int s = 0; s < 4; s++) {
                if constexpr (IS_A) {
                    f4 v = rf[s];
                    h4 hv = {(_Float16)v.x, (_Float16)v.y, (_Float16)v.z, (_Float16)v.w};
                    *(h4*)&sm[wbase + s * XS + prow * PX + pcol * 4] = hv;
                } else {
                    *(h8*)&sm[wbase + s * XS + prow * PX + pcol * 8] = rh[s];
                }
            }
#pragma unroll
            for (int s = 0; s < 4; s++) {
                int tt = t + 5 + s; if (tt > T_STEPS - 1) tt = T_STEPS - 1;
                if constexpr (IS_A)
                    rf[s] = *(const f4*)&xA[(size_t)((b0 + prow) * T_STEPS + tt) * FDIM + pcol * 4];
                else
                    rh[s] = *(const h8*)&xB[((size_t)tt * BATCH + b0 + prow) * NU + pcol * 8];
            }
        }
        __syncthreads();
    }

    if constexpr (!IS_A) {
        // h(T): t=255 (p=1) wrote into H0
        if (wv == 0) {
            int rw = lane >> 5, u = lane & 31;
            float s = 0.0f;
#pragma unroll
            for (int j = 0; j < 4; j++) {
                int uum = u + j * 32;
                s += (float)sm[H0 + rw * PH + uum] * Wd[uum];
            }
            s += __shfl_xor(s, 16);
            s += __shfl_xor(s, 8);
            s += __shfl_xor(s, 4);
            s += __shfl_xor(s, 2);
            s += __shfl_xor(s, 1);
            if ((lane & 31) == 0) dout[b0 + rw] = fmaxf(s + bd[0], 0.0f);
        }
    }
}

extern "C" void kernel_launch(void* const* d_in, const int* in_sizes, int n_in,
                              void* d_out, int out_size, void* d_ws, size_t ws_size,
                              hipStream_t stream) {
    const float* x  = (const float*)d_in[0];
    const float* W1 = (const float*)d_in[1];
    const float* U1 = (const float*)d_in[2];
    const float* b1 = (const float*)d_in[3];
    const float* W2 = (const float*)d_in[4];
    const float* U2 = (const float*)d_in[5];
    const float* b2 = (const float*)d_in[6];
    const float* Wd = (const float*)d_in[7];
    const float* bd = (const float*)d_in[8];
    float* out = (float*)d_out;

    const size_t HS   = 33554432;              // hs fp16 [256][512][128]
    const size_t oWp1 = HS;
    const size_t oUp1 = oWp1 + 65536;
    const size_t oWp2 = oUp1 + 131072;
    const size_t oUp2 = oWp2 + 131072;
    const size_t oBp1 = oUp2 + 131072;
    const size_t oBp2 = oBp1 + 2048;
    const size_t need = oBp2 + 2048;           // 34,017,280
    if (ws_size < need) return;

    char* ws = (char*)d_ws;
    _Float16* hs  = (_Float16*)ws;
    _Float16* Wp1 = (_Float16*)(ws + oWp1);
    _Float16* Up1 = (_Float16*)(ws + oUp1);
    _Float16* Wp2 = (_Float16*)(ws + oWp2);
    _Float16* Up2 = (_Float16*)(ws + oUp2);
    float*    bp1 = (float*)(ws + oBp1);
    float*    bp2 = (float*)(ws + oBp2);

    prep_weights<<<900, 256, 0, stream>>>(W1, U1, b1, W2, U2, b2,
                                          Wp1, Up1, Wp2, Up2, bp1, bp2);
    lstm_layer<true><<<256, 512, 0, stream>>>(x, nullptr, Wp1, Up1, bp1,
                                              hs, nullptr, nullptr, nullptr);
    lstm_layer<false><<<256, 512, 0, stream>>>(nullptr, hs, Wp2, Up2, bp2,
                                               nullptr, Wd, bd, out);
}

// Round 6
// 417.982 us; speedup vs baseline: 1.2262x; 1.0931x over previous
//
#include <hip/hip_runtime.h>

// SimpleLSTM: 2-layer LSTM (B=512,T=256,F=64,U=128) + Dense(1,relu).
// Round-6 insight: kernel is MFMA-ISSUE-bound (19.4 cyc/SIMD per 16x16x32
// MFMA), 87.5% M-waste on 2 rows/WG. Recurrent h@U can't pack M (serial),
// but x@W across timesteps CAN: compute xz for 8 future steps per block
// with M=16 fully packed (8 steps x 2 rows), 8x fewer x-side MFMAs.
// Per-step path: 16 h@U MFMAs + gate epilogue. xz ring in LDS, bias folded.
// 256 WGs x 512 thr, 2 batch rows/WG, 1 barrier/step.

#define T_STEPS 256
#define BATCH   512
#define NU      128
#define FDIM    64

typedef _Float16 h8 __attribute__((ext_vector_type(8)));
typedef _Float16 h4 __attribute__((ext_vector_type(4)));
typedef float    f4 __attribute__((ext_vector_type(4)));

#define LOG2E    1.4426950408889634f
#define TWOLOG2E 2.8853900817779268f

#if __has_builtin(__builtin_amdgcn_exp2f)
#define EXP2F(x) __builtin_amdgcn_exp2f(x)
#else
#define EXP2F(x) exp2f(x)
#endif
#if __has_builtin(__builtin_amdgcn_rcpf)
#define RCPF(x) __builtin_amdgcn_rcpf(x)
#else
#define RCPF(x) (1.0f / (x))
#endif

__device__ __forceinline__ float sigm2(float s) {   // s = z*log2e
    return RCPF(1.0f + EXP2F(-s));
}
__device__ __forceinline__ float tanh2(float t) {   // t = 2*z*log2e
    return 1.0f - 2.0f * RCPF(1.0f + EXP2F(t));
}

// ---- weight prep: transpose to col-major [col][k], cast fp16, fold log2e ----
__global__ void prep_weights(const float* __restrict__ W1, const float* __restrict__ U1,
                             const float* __restrict__ b1, const float* __restrict__ W2,
                             const float* __restrict__ U2, const float* __restrict__ b2,
                             _Float16* __restrict__ Wp1, _Float16* __restrict__ Up1,
                             _Float16* __restrict__ Wp2, _Float16* __restrict__ Up2,
                             float* __restrict__ bp1, float* __restrict__ bp2) {
    int i = blockIdx.x * 256 + threadIdx.x;
    if (i < 32768) {                       // Wp1 [512][64] from W1 [64][512]
        int col = i >> 6, k = i & 63;
        float sc = ((col >> 7) == 2) ? TWOLOG2E : LOG2E;
        Wp1[i] = (_Float16)(W1[k * 512 + col] * sc);
    } else if (i < 32768 + 65536) {        // Up1 [512][128] from U1 [128][512]
        int j = i - 32768; int col = j >> 7, k = j & 127;
        float sc = ((col >> 7) == 2) ? TWOLOG2E : LOG2E;
        Up1[j] = (_Float16)(U1[k * 512 + col] * sc);
    } else if (i < 32768 + 131072) {       // Wp2 [512][128] from W2 [128][512]
        int j = i - 98304; int col = j >> 7, k = j & 127;
        float sc = ((col >> 7) == 2) ? TWOLOG2E : LOG2E;
        Wp2[j] = (_Float16)(W2[k * 512 + col] * sc);
    } else if (i < 32768 + 196608) {       // Up2 [512][128] from U2 [128][512]
        int j = i - 163840; int col = j >> 7, k = j & 127;
        float sc = ((col >> 7) == 2) ? TWOLOG2E : LOG2E;
        Up2[j] = (_Float16)(U2[k * 512 + col] * sc);
    } else if (i < 32768 + 196608 + 1024) {
        int j = i - 229376;
        if (j < 512) {
            float sc = ((j >> 7) == 2) ? TWOLOG2E : LOG2E;
            bp1[j] = b1[j] * sc;
        } else {
            int col = j - 512;
            float sc = ((col >> 7) == 2) ? TWOLOG2E : LOG2E;
            bp2[col] = b2[col] * sc;
        }
    }
}

// ---- LSTM layer kernel ----
// IS_A: input = x (f32 [B,T,F]), writes hs fp16 [T,B,U].
// !IS_A: input = hs (fp16 [T,B,U]), fused dense at end.
template <bool IS_A>
__attribute__((amdgpu_waves_per_eu(2, 2)))
__global__ __launch_bounds__(512) void lstm_layer(
    const float* __restrict__ xA, const _Float16* __restrict__ xB,
    const _Float16* __restrict__ Wp,   // [512][KX] col-major, scaled fp16
    const _Float16* __restrict__ Up,   // [512][128] col-major, scaled fp16
    const float* __restrict__ bp,      // [512] scaled
    _Float16* __restrict__ hs_out,
    const float* __restrict__ Wd, const float* __restrict__ bd,
    float* __restrict__ dout) {
    constexpr int KX  = IS_A ? 64 : 128;
    constexpr int KXS = KX / 32;
    constexpr int PH  = 136;            // halfs
    constexpr int H0  = 0;              // h buffers: 2 rows x PH, double
    constexpr int H1  = 2 * PH;
    constexpr int XZ  = 4 * PH;         // xz ring: 2 halves
    constexpr int XZH = 8 * NU * 8;     // per half: [8 s][128 u][2 row][4 g] halfs
    constexpr int SMH = XZ + 2 * XZH;

    __shared__ __align__(16) _Float16 sm[SMH];

    const int tid  = threadIdx.x;
    const int lane = tid & 63;
    const int wv   = tid >> 6;       // 0..7, each owns 16 units x 4 gates
    const int m    = lane & 15;
    const int kc   = lane >> 4;      // quad 0..3
    const int u0   = wv * 16;
    const int b0   = blockIdx.x * 2;

    // zero h region (h0 = 0 for t=0)
    for (int i = tid; i < 4 * PH; i += 512) sm[i] = (_Float16)0.0f;

    // B-fragments: B[k=kc*8+j][n=col], col-major source
    h8 uf[4][4];                       // hot: used every step
#pragma unroll
    for (int g = 0; g < 4; g++)
#pragma unroll
        for (int ks = 0; ks < 4; ks++)
            uf[g][ks] = *(const h8*)&Up[(g * 128 + u0 + m) * 128 + ks * 32 + kc * 8];
    h8 wf[4][KXS];                     // cold: used once per 8 steps
#pragma unroll
    for (int g = 0; g < 4; g++)
#pragma unroll
        for (int ks = 0; ks < KXS; ks++)
            wf[g][ks] = *(const h8*)&Wp[(g * 128 + u0 + m) * KX + ks * 32 + kc * 8];
    float bias[4];
#pragma unroll
    for (int g = 0; g < 4; g++) bias[g] = bp[g * 128 + u0 + m];

    // ---- x-block machinery: packed-M x-projection, 8 steps at a time ----
    // A rows: r16 = s*2 + brow (s=step-in-block, brow=batch row). Lane m -> row m.
    f4 rX[4]; h8 rH[4];
    auto loadA = [&](int kblk) {       // prefetch A-frags for block kblk -> regs
        int tt = kblk * 8 + (m >> 1); if (tt > T_STEPS - 1) tt = T_STEPS - 1;
        const int bb = b0 + (m & 1);
        if constexpr (IS_A) {
#pragma unroll
            for (int ks = 0; ks < KXS; ks++)
#pragma unroll
                for (int hf = 0; hf < 2; hf++)
                    rX[ks * 2 + hf] = *(const f4*)&xA[((size_t)bb * T_STEPS + tt) * FDIM
                                                      + ks * 32 + kc * 8 + hf * 4];
        } else {
#pragma unroll
            for (int ks = 0; ks < 4; ks++)
                rH[ks] = *(const h8*)&xB[((size_t)tt * BATCH + bb) * NU + ks * 32 + kc * 8];
        }
    };
    auto calcX = [&](int kblk) {       // consume regs -> xz half (kblk&1)
        _Float16* xzw = &sm[XZ + (kblk & 1) * XZH];
        f4 accx[4];
#pragma unroll
        for (int g = 0; g < 4; g++) accx[g] = (f4){bias[g], bias[g], bias[g], bias[g]};
#pragma unroll
        for (int ks = 0; ks < KXS; ks++) {
            h8 a;
            if constexpr (IS_A) {
#pragma unroll
                for (int j = 0; j < 4; j++) {
                    a[j]     = (_Float16)rX[ks * 2][j];
                    a[4 + j] = (_Float16)rX[ks * 2 + 1][j];
                }
            } else {
                a = rH[ks];
            }
#pragma unroll
            for (int g = 0; g < 4; g++)
                accx[g] = __builtin_amdgcn_mfma_f32_16x16x32_f16(a, wf[g][ks], accx[g], 0, 0, 0);
        }
        // C/D: col=lane&15, row=kc*4+r. row -> (s=row>>1, brow=row&1).
#pragma unroll
        for (int g = 0; g < 4; g++)
#pragma unroll
            for (int r = 0; r < 4; r++) {
                int r16 = kc * 4 + r;
                xzw[(((r16 >> 1) * 128 + u0 + m) * 2 + (r16 & 1)) * 4 + g] =
                    (_Float16)accx[g][r];
            }
    };

    loadA(0); calcX(0);                // block 0 -> half 0
    loadA(1);                          // prefetch block 1
    __syncthreads();                   // xz half0 + zeroed H visible

    const h8 hzero = {};
    h8 ha[4];
#pragma unroll
    for (int ks = 0; ks < 4; ks++) ha[ks] = hzero;

    float c0 = 0.0f, c1 = 0.0f;

#pragma unroll 8
    for (int t = 0; t < T_STEPS; t++) {
        const int p = t & 1;
        const int s = t & 7;

        if (s == 0) {
            int kn = (t >> 3) + 1;
            if (kn < T_STEPS / 8) {
                calcX(kn);             // regs hold block kn (prefetched)
                loadA(kn + 1);         // prefetch next (clamped)
            }
        }

        // xz for (this step, this wave's 16 units): one b128 per lane<16
        h8 xzf = hzero;
        if (lane < 16)
            xzf = *(const h8*)&sm[XZ + ((t >> 3) & 1) * XZH + (s * 128 + u0 + m) * 8];
        f4 acc[4];
#pragma unroll
        for (int g = 0; g < 4; g++)
            acc[g] = (f4){(float)xzf[g], (float)xzf[4 + g], 0.0f, 0.0f};

        // A-frags for h@U: rows 0,1 real; lanes m>=2 keep stale regs
        if (m < 2) {
            const _Float16* hb = &sm[p ? H1 : H0];
#pragma unroll
            for (int ks = 0; ks < 4; ks++)
                ha[ks] = *(const h8*)&hb[m * PH + ks * 32 + kc * 8];
        }
#pragma unroll
        for (int ks = 0; ks < 4; ks++)
#pragma unroll
            for (int g = 0; g < 4; g++)
                acc[g] = __builtin_amdgcn_mfma_f32_16x16x32_f16(ha[ks], uf[g][ks], acc[g], 0, 0, 0);

        // gate epilogue (bias already in xz): rows 0,1 in regs 0,1 of lanes<16
        if (lane < 16) {
            float gi0 = sigm2(acc[0][0]), gf0 = sigm2(acc[1][0]);
            float gg0 = tanh2(acc[2][0]), go0 = sigm2(acc[3][0]);
            c0 = gf0 * c0 + gi0 * gg0;
            float hv0 = go0 * tanh2(c0 * TWOLOG2E);
            float gi1 = sigm2(acc[0][1]), gf1 = sigm2(acc[1][1]);
            float gg1 = tanh2(acc[2][1]), go1 = sigm2(acc[3][1]);
            c1 = gf1 * c1 + gi1 * gg1;
            float hv1 = go1 * tanh2(c1 * TWOLOG2E);
            _Float16 h0v = (_Float16)hv0, h1v = (_Float16)hv1;
            _Float16* hbn = &sm[p ? H0 : H1];
            hbn[u0 + m] = h0v;
            hbn[PH + u0 + m] = h1v;
            if constexpr (IS_A) {
                hs_out[((size_t)t * BATCH + b0    ) * NU + u0 + m] = h0v;
                hs_out[((size_t)t * BATCH + b0 + 1) * NU + u0 + m] = h1v;
            }
        }
        __syncthreads();
    }

    if constexpr (!IS_A) {
        // h(T): t=255 (p=1) wrote into H0
        if (wv == 0) {
            int rw = lane >> 5, u = lane & 31;
            float sacc = 0.0f;
#pragma unroll
            for (int j = 0; j < 4; j++) {
                int uum = u + j * 32;
                sacc += (float)sm[H0 + rw * PH + uum] * Wd[uum];
            }
            sacc += __shfl_xor(sacc, 16);
            sacc += __shfl_xor(sacc, 8);
            sacc += __shfl_xor(sacc, 4);
            sacc += __shfl_xor(sacc, 2);
            sacc += __shfl_xor(sacc, 1);
            if ((lane & 31) == 0) dout[b0 + rw] = fmaxf(sacc + bd[0], 0.0f);
        }
    }
}

extern "C" void kernel_launch(void* const* d_in, const int* in_sizes, int n_in,
                              void* d_out, int out_size, void* d_ws, size_t ws_size,
                              hipStream_t stream) {
    const float* x  = (const float*)d_in[0];
    const float* W1 = (const float*)d_in[1];
    const float* U1 = (const float*)d_in[2];
    const float* b1 = (const float*)d_in[3];
    const float* W2 = (const float*)d_in[4];
    const float* U2 = (const float*)d_in[5];
    const float* b2 = (const float*)d_in[6];
    const float* Wd = (const float*)d_in[7];
    const float* bd = (const float*)d_in[8];
    float* out = (float*)d_out;

    const size_t HS   = 33554432;              // hs fp16 [256][512][128]
    const size_t oWp1 = HS;
    const size_t oUp1 = oWp1 + 65536;
    const size_t oWp2 = oUp1 + 131072;
    const size_t oUp2 = oWp2 + 131072;
    const size_t oBp1 = oUp2 + 131072;
    const size_t oBp2 = oBp1 + 2048;
    const size_t need = oBp2 + 2048;           // 34,017,280
    if (ws_size < need) return;

    char* ws = (char*)d_ws;
    _Float16* hs  = (_Float16*)ws;
    _Float16* Wp1 = (_Float16*)(ws + oWp1);
    _Float16* Up1 = (_Float16*)(ws + oUp1);
    _Float16* Wp2 = (_Float16*)(ws + oWp2);
    _Float16* Up2 = (_Float16*)(ws + oUp2);
    float*    bp1 = (float*)(ws + oBp1);
    float*    bp2 = (float*)(ws + oBp2);

    prep_weights<<<900, 256, 0, stream>>>(W1, U1, b1, W2, U2, b2,
                                          Wp1, Up1, Wp2, Up2, bp1, bp2);
    lstm_layer<true><<<256, 512, 0, stream>>>(x, nullptr, Wp1, Up1, bp1,
                                              hs, nullptr, nullptr, nullptr);
    lstm_layer<false><<<256, 512, 0, stream>>>(nullptr, hs, Wp2, Up2, bp2,
                                               nullptr, Wd, bd, out);
}

// Round 7
// 358.228 us; speedup vs baseline: 1.4308x; 1.1668x over previous
//
#include <hip/hip_runtime.h>

// SimpleLSTM: 2-layer LSTM (B=512,T=256,F=64,U=128) + Dense(1,relu).
// R7: (a) raw LDS-only barrier in step loop (no vmcnt drain -> prefetch and
// stores stay in flight); (b) batch row 1 mapped to MFMA A-row 4 so epilogue
// runs on 32 lanes with zero cross-lane moves; (c) xz kept f32 in LDS,
// added in epilogue; gate signs folded into prepped weights.
// 256 WGs x 512 thr, 2 batch rows/WG; x@W packed M=16 for 8 steps/block.

#define T_STEPS 256
#define BATCH   512
#define NU      128
#define FDIM    64

typedef _Float16 h8 __attribute__((ext_vector_type(8)));
typedef _Float16 h4 __attribute__((ext_vector_type(4)));
typedef float    f4 __attribute__((ext_vector_type(4)));

#define LOG2E    1.4426950408889634f
#define TWOLOG2E 2.8853900817779268f

// Workgroup barrier draining LDS only. All cross-step dependencies are LDS
// (ds_*); global loads are consumed via compiler-inserted vmcnt waits at use,
// and global stores have no intra-kernel reader. Avoids the s_waitcnt
// vmcnt(0) the compiler emits before s_barrier for __syncthreads.
#define WG_BARRIER() asm volatile("s_waitcnt lgkmcnt(0)\n\ts_barrier" ::: "memory")

#if __has_builtin(__builtin_amdgcn_exp2f)
#define EXP2F(x) __builtin_amdgcn_exp2f(x)
#else
#define EXP2F(x) exp2f(x)
#endif
#if __has_builtin(__builtin_amdgcn_rcpf)
#define RCPF(x) __builtin_amdgcn_rcpf(x)
#else
#define RCPF(x) (1.0f / (x))
#endif

// s = -z*log2e (sign folded into weights) -> sigmoid(z)
__device__ __forceinline__ float sigm2(float s) {
    return RCPF(1.0f + EXP2F(s));
}
// t = 2*z*log2e -> tanh(z)
__device__ __forceinline__ float tanh2(float t) {
    return 1.0f - 2.0f * RCPF(1.0f + EXP2F(t));
}

// ---- weight prep: col-major [col][k], fp16, fold gate-specific log2e ----
// gates: 0=i 1=f 2=g 3=o ; i/f/o scaled by -log2e (sigm2), g by +2log2e.
__global__ void prep_weights(const float* __restrict__ W1, const float* __restrict__ U1,
                             const float* __restrict__ b1, const float* __restrict__ W2,
                             const float* __restrict__ U2, const float* __restrict__ b2,
                             _Float16* __restrict__ Wp1, _Float16* __restrict__ Up1,
                             _Float16* __restrict__ Wp2, _Float16* __restrict__ Up2,
                             float* __restrict__ bp1, float* __restrict__ bp2) {
    int i = blockIdx.x * 256 + threadIdx.x;
    if (i < 32768) {                       // Wp1 [512][64] from W1 [64][512]
        int col = i >> 6, k = i & 63;
        float sc = ((col >> 7) == 2) ? TWOLOG2E : -LOG2E;
        Wp1[i] = (_Float16)(W1[k * 512 + col] * sc);
    } else if (i < 32768 + 65536) {        // Up1 [512][128] from U1 [128][512]
        int j = i - 32768; int col = j >> 7, k = j & 127;
        float sc = ((col >> 7) == 2) ? TWOLOG2E : -LOG2E;
        Up1[j] = (_Float16)(U1[k * 512 + col] * sc);
    } else if (i < 32768 + 131072) {       // Wp2 [512][128] from W2 [128][512]
        int j = i - 98304; int col = j >> 7, k = j & 127;
        float sc = ((col >> 7) == 2) ? TWOLOG2E : -LOG2E;
        Wp2[j] = (_Float16)(W2[k * 512 + col] * sc);
    } else if (i < 32768 + 196608) {       // Up2 [512][128] from U2 [128][512]
        int j = i - 163840; int col = j >> 7, k = j & 127;
        float sc = ((col >> 7) == 2) ? TWOLOG2E : -LOG2E;
        Up2[j] = (_Float16)(U2[k * 512 + col] * sc);
    } else if (i < 32768 + 196608 + 1024) {
        int j = i - 229376;
        if (j < 512) {
            float sc = ((j >> 7) == 2) ? TWOLOG2E : -LOG2E;
            bp1[j] = b1[j] * sc;
        } else {
            int col = j - 512;
            float sc = ((col >> 7) == 2) ? TWOLOG2E : -LOG2E;
            bp2[col] = b2[col] * sc;
        }
    }
}

// ---- LSTM layer kernel ----
// IS_A: input = x (f32 [B,T,F]), writes hs fp16 [T,B,U].
// !IS_A: input = hs (fp16 [T,B,U]), fused dense at end.
template <bool IS_A>
__attribute__((amdgpu_waves_per_eu(2, 2)))
__global__ __launch_bounds__(512) void lstm_layer(
    const float* __restrict__ xA, const _Float16* __restrict__ xB,
    const _Float16* __restrict__ Wp,   // [512][KX] col-major, scaled fp16
    const _Float16* __restrict__ Up,   // [512][128] col-major, scaled fp16
    const float* __restrict__ bp,      // [512] scaled
    _Float16* __restrict__ hs_out,
    const float* __restrict__ Wd, const float* __restrict__ bd,
    float* __restrict__ dout) {
    constexpr int KX  = IS_A ? 64 : 128;
    constexpr int KXS = KX / 32;
    constexpr int PH  = 136;            // halfs; h rows 0/1 at 0 and PH
    constexpr int H0  = 0;              // h buffers: 2 rows x PH, double
    constexpr int H1  = 2 * PH;

    __shared__ __align__(16) _Float16 smh[4 * PH];
    // xz: [half][s][u][row][gate] f32 = 2*8*128*2*4 floats = 64 KB
    __shared__ __align__(16) float smxz[2 * 8 * 128 * 2 * 4];

    const int tid  = threadIdx.x;
    const int lane = tid & 63;
    const int wv   = tid >> 6;       // 0..7, each owns 16 units x 4 gates
    const int m    = lane & 15;
    const int kc   = lane >> 4;      // quad 0..3
    const int u0   = wv * 16;
    const int b0   = blockIdx.x * 2;

    // zero h region (h0 = 0 for t=0)
    for (int i = tid; i < 4 * PH; i += 512) smh[i] = (_Float16)0.0f;

    // B-fragments: B[k=kc*8+j][n=col], col-major source
    h8 uf[4][4];                       // hot: every step
#pragma unroll
    for (int g = 0; g < 4; g++)
#pragma unroll
        for (int ks = 0; ks < 4; ks++)
            uf[g][ks] = *(const h8*)&Up[(g * 128 + u0 + m) * 128 + ks * 32 + kc * 8];
    h8 wf[4][KXS];                     // cold: once per 8 steps
#pragma unroll
    for (int g = 0; g < 4; g++)
#pragma unroll
        for (int ks = 0; ks < KXS; ks++)
            wf[g][ks] = *(const h8*)&Wp[(g * 128 + u0 + m) * KX + ks * 32 + kc * 8];
    float bias[4];
#pragma unroll
    for (int g = 0; g < 4; g++) bias[g] = bp[g * 128 + u0 + m];

    // ---- x-block: packed-M x-projection, 8 steps/block ----
    // A row r16 = s*2 + brow; lane m -> row m -> (step m>>1, batch row m&1).
    f4 rX[4]; h8 rH[4];
    auto loadA = [&](int kblk) {
        int tt = kblk * 8 + (m >> 1); if (tt > T_STEPS - 1) tt = T_STEPS - 1;
        const int bb = b0 + (m & 1);
        if constexpr (IS_A) {
#pragma unroll
            for (int ks = 0; ks < KXS; ks++)
#pragma unroll
                for (int hf = 0; hf < 2; hf++)
                    rX[ks * 2 + hf] = *(const f4*)&xA[((size_t)bb * T_STEPS + tt) * FDIM
                                                      + ks * 32 + kc * 8 + hf * 4];
        } else {
#pragma unroll
            for (int ks = 0; ks < 4; ks++)
                rH[ks] = *(const h8*)&xB[((size_t)tt * BATCH + bb) * NU + ks * 32 + kc * 8];
        }
    };
    auto calcX = [&](int kblk) {       // regs -> xz half (kblk&1), f32
        float* xzw = &smxz[(kblk & 1) * 8192];
        f4 accx[4];
#pragma unroll
        for (int g = 0; g < 4; g++) accx[g] = (f4){bias[g], bias[g], bias[g], bias[g]};
#pragma unroll
        for (int ks = 0; ks < KXS; ks++) {
            h8 a;
            if constexpr (IS_A) {
#pragma unroll
                for (int j = 0; j < 4; j++) {
                    a[j]     = (_Float16)rX[ks * 2][j];
                    a[4 + j] = (_Float16)rX[ks * 2 + 1][j];
                }
            } else {
                a = rH[ks];
            }
#pragma unroll
            for (int g = 0; g < 4; g++)
                accx[g] = __builtin_amdgcn_mfma_f32_16x16x32_f16(a, wf[g][ks], accx[g], 0, 0, 0);
        }
        // C/D row r16 = kc*4+rr -> (s=r16>>1, brow=r16&1); layout [s][u][row][g]
#pragma unroll
        for (int g = 0; g < 4; g++)
#pragma unroll
            for (int rr = 0; rr < 4; rr++) {
                int r16 = kc * 4 + rr;
                xzw[(((r16 >> 1) * 128 + u0 + m) * 2 + (r16 & 1)) * 4 + g] = accx[g][rr];
            }
    };

    loadA(0); calcX(0);                // block 0 -> half 0
    loadA(1);                          // in flight for block 1
    __syncthreads();                   // xz half0 + zeroed H visible

    const h8 hzero = {};
    h8 ha[4];
#pragma unroll
    for (int ks = 0; ks < 4; ks++) ha[ks] = hzero;

    // epilogue identity: lanes 0..31 own (row=lane>>4, unit=u0+(lane&15))
    const int erow = lane >> 4;        // valid for lane<32
    float cst = 0.0f;

#pragma unroll 8
    for (int t = 0; t < T_STEPS; t++) {
        const int p = t & 1;
        const int s = t & 7;

        if (s == 0) {
            int kn = (t >> 3) + 1;
            if (kn < T_STEPS / 8) {
                calcX(kn);             // consumes regs loaded 8 steps ago
                loadA(kn + 1);         // issue next block's loads (clamped)
            }
        }

        // A-frags for h@U: batch row 0 -> A-row 0 (m==0), row 1 -> A-row 4
        // (m==4) so C-row 4 lands in lanes 16..31 reg 0. Other rows garbage.
        if (m == 0 || m == 4) {
            const _Float16* hb = &smh[(p ? H1 : H0) + (m == 4 ? PH : 0)];
#pragma unroll
            for (int ks = 0; ks < 4; ks++)
                ha[ks] = *(const h8*)&hb[ks * 32 + kc * 8];
        }

        f4 acc[4];
#pragma unroll
        for (int g = 0; g < 4; g++) acc[g] = (f4){0.f, 0.f, 0.f, 0.f};
#pragma unroll
        for (int ks = 0; ks < 4; ks++)
#pragma unroll
            for (int g = 0; g < 4; g++)
                acc[g] = __builtin_amdgcn_mfma_f32_16x16x32_f16(ha[ks], uf[g][ks], acc[g], 0, 0, 0);

        // epilogue on 32 lanes; z = acc[g][0] + xz (f32, exact)
        if (lane < 32) {
            const f4 xzv = *(const f4*)&smxz[((t >> 3) & 1) * 8192
                                             + ((s * 128 + u0 + m) * 2 + erow) * 4];
            float gi = sigm2(acc[0][0] + xzv[0]);
            float gf = sigm2(acc[1][0] + xzv[1]);
            float gg = tanh2(acc[2][0] + xzv[2]);
            float go = sigm2(acc[3][0] + xzv[3]);
            cst = gf * cst + gi * gg;
            float hv = go * tanh2(cst * TWOLOG2E);
            _Float16 h16 = (_Float16)hv;
            smh[(p ? H0 : H1) + erow * PH + u0 + m] = h16;
            if constexpr (IS_A)
                hs_out[((size_t)t * BATCH + b0 + erow) * NU + u0 + m] = h16;
        }
        WG_BARRIER();                  // LDS-only drain; vm stays in flight
    }

    if constexpr (!IS_A) {
        // h(T): t=255 (p=1) wrote into H0
        if (wv == 0) {
            int rw = lane >> 5, u = lane & 31;
            float sacc = 0.0f;
#pragma unroll
            for (int j = 0; j < 4; j++) {
                int uum = u + j * 32;
                sacc += (float)smh[H0 + rw * PH + uum] * Wd[uum];
            }
            sacc += __shfl_xor(sacc, 16);
            sacc += __shfl_xor(sacc, 8);
            sacc += __shfl_xor(sacc, 4);
            sacc += __shfl_xor(sacc, 2);
            sacc += __shfl_xor(sacc, 1);
            if ((lane & 31) == 0) dout[b0 + rw] = fmaxf(sacc + bd[0], 0.0f);
        }
    }
}

extern "C" void kernel_launch(void* const* d_in, const int* in_sizes, int n_in,
                              void* d_out, int out_size, void* d_ws, size_t ws_size,
                              hipStream_t stream) {
    const float* x  = (const float*)d_in[0];
    const float* W1 = (const float*)d_in[1];
    const float* U1 = (const float*)d_in[2];
    const float* b1 = (const float*)d_in[3];
    const float* W2 = (const float*)d_in[4];
    const float* U2 = (const float*)d_in[5];
    const float* b2 = (const float*)d_in[6];
    const float* Wd = (const float*)d_in[7];
    const float* bd = (const float*)d_in[8];
    float* out = (float*)d_out;

    const size_t HS   = 33554432;              // hs fp16 [256][512][128]
    const size_t oWp1 = HS;
    const size_t oUp1 = oWp1 + 65536;
    const size_t oWp2 = oUp1 + 131072;
    const size_t oUp2 = oWp2 + 131072;
    const size_t oBp1 = oUp2 + 131072;
    const size_t oBp2 = oBp1 + 2048;
    const size_t need = oBp2 + 2048;           // 34,017,280
    if (ws_size < need) return;

    char* ws = (char*)d_ws;
    _Float16* hs  = (_Float16*)ws;
    _Float16* Wp1 = (_Float16*)(ws + oWp1);
    _Float16* Up1 = (_Float16*)(ws + oUp1);
    _Float16* Wp2 = (_Float16*)(ws + oWp2);
    _Float16* Up2 = (_Float16*)(ws + oUp2);
    float*    bp1 = (float*)(ws + oBp1);
    float*    bp2 = (float*)(ws + oBp2);

    prep_weights<<<900, 256, 0, stream>>>(W1, U1, b1, W2, U2, b2,
                                          Wp1, Up1, Wp2, Up2, bp1, bp2);
    lstm_layer<true><<<256, 512, 0, stream>>>(x, nullptr, Wp1, Up1, bp1,
                                              hs, nullptr, nullptr, nullptr);
    lstm_layer<false><<<256, 512, 0, stream>>>(nullptr, hs, Wp2, Up2, bp2,
                                               nullptr, Wd, bd, out);
}

// Round 8
// 350.490 us; speedup vs baseline: 1.4624x; 1.0221x over previous
//
#include <hip/hip_runtime.h>

// SimpleLSTM: 2-layer LSTM (B=512,T=256,F=64,U=128) + Dense(1,relu).
// R8: conflict-free xz layout [half][r16][u] f4 (consecutive 16B/lane reads,
// b128 gate-vector writes), unroll-16 compile-time LDS addressing, zero-C
// MFMA init. Raw LDS-only barrier; 32-lane epilogue; x@W packed M=16 per
// 8-step block. 256 WGs x 512 thr, 2 batch rows/WG.

#define T_STEPS 256
#define BATCH   512
#define NU      128
#define FDIM    64

typedef _Float16 h8 __attribute__((ext_vector_type(8)));
typedef _Float16 h4 __attribute__((ext_vector_type(4)));
typedef float    f4 __attribute__((ext_vector_type(4)));

#define LOG2E    1.4426950408889634f
#define TWOLOG2E 2.8853900817779268f

// Workgroup barrier draining LDS only (no vmcnt drain; all cross-step deps
// are LDS, global loads wait at use, stores have no in-kernel reader).
#define WG_BARRIER() asm volatile("s_waitcnt lgkmcnt(0)\n\ts_barrier" ::: "memory")

#if __has_builtin(__builtin_amdgcn_exp2f)
#define EXP2F(x) __builtin_amdgcn_exp2f(x)
#else
#define EXP2F(x) exp2f(x)
#endif
#if __has_builtin(__builtin_amdgcn_rcpf)
#define RCPF(x) __builtin_amdgcn_rcpf(x)
#else
#define RCPF(x) (1.0f / (x))
#endif

// s = -z*log2e (sign folded into weights) -> sigmoid(z)
__device__ __forceinline__ float sigm2(float s) {
    return RCPF(1.0f + EXP2F(s));
}
// t = 2*z*log2e -> tanh(z)
__device__ __forceinline__ float tanh2(float t) {
    return 1.0f - 2.0f * RCPF(1.0f + EXP2F(t));
}

// ---- weight prep: col-major [col][k], fp16, fold gate-specific log2e ----
// gates: 0=i 1=f 2=g 3=o ; i/f/o scaled by -log2e (sigm2), g by +2log2e.
__global__ void prep_weights(const float* __restrict__ W1, const float* __restrict__ U1,
                             const float* __restrict__ b1, const float* __restrict__ W2,
                             const float* __restrict__ U2, const float* __restrict__ b2,
                             _Float16* __restrict__ Wp1, _Float16* __restrict__ Up1,
                             _Float16* __restrict__ Wp2, _Float16* __restrict__ Up2,
                             float* __restrict__ bp1, float* __restrict__ bp2) {
    int i = blockIdx.x * 256 + threadIdx.x;
    if (i < 32768) {                       // Wp1 [512][64] from W1 [64][512]
        int col = i >> 6, k = i & 63;
        float sc = ((col >> 7) == 2) ? TWOLOG2E : -LOG2E;
        Wp1[i] = (_Float16)(W1[k * 512 + col] * sc);
    } else if (i < 32768 + 65536) {        // Up1 [512][128] from U1 [128][512]
        int j = i - 32768; int col = j >> 7, k = j & 127;
        float sc = ((col >> 7) == 2) ? TWOLOG2E : -LOG2E;
        Up1[j] = (_Float16)(U1[k * 512 + col] * sc);
    } else if (i < 32768 + 131072) {       // Wp2 [512][128] from W2 [128][512]
        int j = i - 98304; int col = j >> 7, k = j & 127;
        float sc = ((col >> 7) == 2) ? TWOLOG2E : -LOG2E;
        Wp2[j] = (_Float16)(W2[k * 512 + col] * sc);
    } else if (i < 32768 + 196608) {       // Up2 [512][128] from U2 [128][512]
        int j = i - 163840; int col = j >> 7, k = j & 127;
        float sc = ((col >> 7) == 2) ? TWOLOG2E : -LOG2E;
        Up2[j] = (_Float16)(U2[k * 512 + col] * sc);
    } else if (i < 32768 + 196608 + 1024) {
        int j = i - 229376;
        if (j < 512) {
            float sc = ((j >> 7) == 2) ? TWOLOG2E : -LOG2E;
            bp1[j] = b1[j] * sc;
        } else {
            int col = j - 512;
            float sc = ((col >> 7) == 2) ? TWOLOG2E : -LOG2E;
            bp2[col] = b2[col] * sc;
        }
    }
}

// ---- LSTM layer kernel ----
// IS_A: input = x (f32 [B,T,F]), writes hs fp16 [T,B,U].
// !IS_A: input = hs (fp16 [T,B,U]), fused dense at end.
template <bool IS_A>
__attribute__((amdgpu_waves_per_eu(2, 2)))
__global__ __launch_bounds__(512) void lstm_layer(
    const float* __restrict__ xA, const _Float16* __restrict__ xB,
    const _Float16* __restrict__ Wp,   // [512][KX] col-major, scaled fp16
    const _Float16* __restrict__ Up,   // [512][128] col-major, scaled fp16
    const float* __restrict__ bp,      // [512] scaled
    _Float16* __restrict__ hs_out,
    const float* __restrict__ Wd, const float* __restrict__ bd,
    float* __restrict__ dout) {
    constexpr int KX  = IS_A ? 64 : 128;
    constexpr int KXS = KX / 32;
    constexpr int PH  = 136;            // halfs; h rows 0/1 at 0 and PH
    constexpr int H0  = 0;              // h buffers: 2 rows x PH, double
    constexpr int H1  = 2 * PH;

    __shared__ __align__(16) _Float16 smh[4 * PH];
    // xz: [half][r16][u] f4, r16 = s*2+row. 2*16*128 f4 = 64 KB.
    __shared__ __align__(16) float smxz[2 * 8192];

    const int tid  = threadIdx.x;
    const int lane = tid & 63;
    const int wv   = tid >> 6;       // 0..7, each owns 16 units x 4 gates
    const int m    = lane & 15;
    const int kc   = lane >> 4;      // quad 0..3
    const int u0   = wv * 16;
    const int b0   = blockIdx.x * 2;

    // zero h region (h0 = 0 for t=0)
    for (int i = tid; i < 4 * PH; i += 512) smh[i] = (_Float16)0.0f;

    // B-fragments: B[k=kc*8+j][n=col], col-major source
    h8 uf[4][4];                       // hot: every step
#pragma unroll
    for (int g = 0; g < 4; g++)
#pragma unroll
        for (int ks = 0; ks < 4; ks++)
            uf[g][ks] = *(const h8*)&Up[(g * 128 + u0 + m) * 128 + ks * 32 + kc * 8];
    h8 wf[4][KXS];                     // cold: once per 8 steps
#pragma unroll
    for (int g = 0; g < 4; g++)
#pragma unroll
        for (int ks = 0; ks < KXS; ks++)
            wf[g][ks] = *(const h8*)&Wp[(g * 128 + u0 + m) * KX + ks * 32 + kc * 8];
    float bias[4];
#pragma unroll
    for (int g = 0; g < 4; g++) bias[g] = bp[g * 128 + u0 + m];

    // ---- x-block: packed-M x-projection, 8 steps/block ----
    // A row r16 = s*2 + brow; lane m supplies row m -> (step m>>1, brow m&1).
    f4 rX[4]; h8 rH[4];
    auto loadA = [&](int kblk) {
        int tt = kblk * 8 + (m >> 1); if (tt > T_STEPS - 1) tt = T_STEPS - 1;
        const int bb = b0 + (m & 1);
        if constexpr (IS_A) {
#pragma unroll
            for (int ks = 0; ks < KXS; ks++)
#pragma unroll
                for (int hf = 0; hf < 2; hf++)
                    rX[ks * 2 + hf] = *(const f4*)&xA[((size_t)bb * T_STEPS + tt) * FDIM
                                                      + ks * 32 + kc * 8 + hf * 4];
        } else {
#pragma unroll
            for (int ks = 0; ks < 4; ks++)
                rH[ks] = *(const h8*)&xB[((size_t)tt * BATCH + bb) * NU + ks * 32 + kc * 8];
        }
    };
    auto calcX = [&](int kblk) {       // regs -> xz half (kblk&1), f32
        float* xzw = &smxz[(kblk & 1) * 8192];
        f4 accx[4];
#pragma unroll
        for (int g = 0; g < 4; g++) accx[g] = (f4){bias[g], bias[g], bias[g], bias[g]};
#pragma unroll
        for (int ks = 0; ks < KXS; ks++) {
            h8 a;
            if constexpr (IS_A) {
#pragma unroll
                for (int j = 0; j < 4; j++) {
                    a[j]     = (_Float16)rX[ks * 2][j];
                    a[4 + j] = (_Float16)rX[ks * 2 + 1][j];
                }
            } else {
                a = rH[ks];
            }
#pragma unroll
            for (int g = 0; g < 4; g++)
                accx[g] = __builtin_amdgcn_mfma_f32_16x16x32_f16(a, wf[g][ks], accx[g], 0, 0, 0);
        }
        // C/D row r16 = kc*4+rr; write gate-vector f4 at [r16][u0+m]
#pragma unroll
        for (int rr = 0; rr < 4; rr++) {
            f4 v = {accx[0][rr], accx[1][rr], accx[2][rr], accx[3][rr]};
            *(f4*)&xzw[((kc * 4 + rr) * 128 + u0 + m) * 4] = v;
        }
    };

    loadA(0); calcX(0);                // block 0 -> half 0
    loadA(1);                          // in flight for block 1
    __syncthreads();                   // xz half0 + zeroed H visible

    const h8 hzero = {};
    h8 ha[4];
#pragma unroll
    for (int ks = 0; ks < 4; ks++) ha[ks] = hzero;

    // loop-invariant zero C for MFMA chain starts (pinned: no per-step remat)
    f4 fzero = (f4){0.f, 0.f, 0.f, 0.f};
    asm volatile("" : "+v"(fzero));

    // epilogue identity: lanes 0..31 own (row=lane>>4, unit=u0+(lane&15))
    const int erow = lane >> 4;        // valid for lane<32
    float cst = 0.0f;

#pragma unroll 16
    for (int t = 0; t < T_STEPS; t++) {
        const int p = t & 1;
        const int s = t & 7;
        const int half = (t >> 3) & 1;

        if (s == 0) {
            int kn = (t >> 3) + 1;
            if (kn < T_STEPS / 8) {
                calcX(kn);             // consumes regs loaded 8 steps ago
                loadA(kn + 1);         // issue next block's loads (clamped)
            }
        }

        // xz gate-vector, issued early (consumed in epilogue)
        f4 xzv;
        if (lane < 32)
            xzv = *(const f4*)&smxz[half * 8192 + (s * 2 + erow) * 512 + (u0 + m) * 4];

        // A-frags for h@U: batch row 0 -> A-row 0 (m==0), row 1 -> A-row 4
        // (m==4) so C-row 4 lands in lanes 16..31 reg 0. Other rows garbage.
        if (m == 0 || m == 4) {
            const _Float16* hb = &smh[(p ? H1 : H0) + (m == 4 ? PH : 0)];
#pragma unroll
            for (int ks = 0; ks < 4; ks++)
                ha[ks] = *(const h8*)&hb[ks * 32 + kc * 8];
        }

        f4 acc[4];
#pragma unroll
        for (int g = 0; g < 4; g++)
            acc[g] = __builtin_amdgcn_mfma_f32_16x16x32_f16(ha[0], uf[g][0], fzero, 0, 0, 0);
#pragma unroll
        for (int ks = 1; ks < 4; ks++)
#pragma unroll
            for (int g = 0; g < 4; g++)
                acc[g] = __builtin_amdgcn_mfma_f32_16x16x32_f16(ha[ks], uf[g][ks], acc[g], 0, 0, 0);

        // epilogue on 32 lanes; z = acc[g][0] + xz (f32, exact)
        if (lane < 32) {
            float gi = sigm2(acc[0][0] + xzv[0]);
            float gf = sigm2(acc[1][0] + xzv[1]);
            float gg = tanh2(acc[2][0] + xzv[2]);
            float go = sigm2(acc[3][0] + xzv[3]);
            cst = gf * cst + gi * gg;
            float hv = go * tanh2(cst * TWOLOG2E);
            _Float16 h16 = (_Float16)hv;
            smh[(p ? H0 : H1) + erow * PH + u0 + m] = h16;
            if constexpr (IS_A)
                hs_out[((size_t)t * BATCH + b0 + erow) * NU + u0 + m] = h16;
        }
        WG_BARRIER();                  // LDS-only drain; vm stays in flight
    }

    if constexpr (!IS_A) {
        // h(T): t=255 (p=1) wrote into H0
        if (wv == 0) {
            int rw = lane >> 5, u = lane & 31;
            float sacc = 0.0f;
#pragma unroll
            for (int j = 0; j < 4; j++) {
                int uum = u + j * 32;
                sacc += (float)smh[H0 + rw * PH + uum] * Wd[uum];
            }
            sacc += __shfl_xor(sacc, 16);
            sacc += __shfl_xor(sacc, 8);
            sacc += __shfl_xor(sacc, 4);
            sacc += __shfl_xor(sacc, 2);
            sacc += __shfl_xor(sacc, 1);
            if ((lane & 31) == 0) dout[b0 + rw] = fmaxf(sacc + bd[0], 0.0f);
        }
    }
}

extern "C" void kernel_launch(void* const* d_in, const int* in_sizes, int n_in,
                              void* d_out, int out_size, void* d_ws, size_t ws_size,
                              hipStream_t stream) {
    const float* x  = (const float*)d_in[0];
    const float* W1 = (const float*)d_in[1];
    const float* U1 = (const float*)d_in[2];
    const float* b1 = (const float*)d_in[3];
    const float* W2 = (const float*)d_in[4];
    const float* U2 = (const float*)d_in[5];
    const float* b2 = (const float*)d_in[6];
    const float* Wd = (const float*)d_in[7];
    const float* bd = (const float*)d_in[8];
    float* out = (float*)d_out;

    const size_t HS   = 33554432;              // hs fp16 [256][512][128]
    const size_t oWp1 = HS;
    const size_t oUp1 = oWp1 + 65536;
    const size_t oWp2 = oUp1 + 131072;
    const size_t oUp2 = oWp2 + 131072;
    const size_t oBp1 = oUp2 + 131072;
    const size_t oBp2 = oBp1 + 2048;
    const size_t need = oBp2 + 2048;           // 34,017,280
    if (ws_size < need) return;

    char* ws = (char*)d_ws;
    _Float16* hs  = (_Float16*)ws;
    _Float16* Wp1 = (_Float16*)(ws + oWp1);
    _Float16* Up1 = (_Float16*)(ws + oUp1);
    _Float16* Wp2 = (_Float16*)(ws + oWp2);
    _Float16* Up2 = (_Float16*)(ws + oUp2);
    float*    bp1 = (float*)(ws + oBp1);
    float*    bp2 = (float*)(ws + oBp2);

    prep_weights<<<900, 256, 0, stream>>>(W1, U1, b1, W2, U2, b2,
                                          Wp1, Up1, Wp2, Up2, bp1, bp2);
    lstm_layer<true><<<256, 512, 0, stream>>>(x, nullptr, Wp1, Up1, bp1,
                                              hs, nullptr, nullptr, nullptr);
    lstm_layer<false><<<256, 512, 0, stream>>>(nullptr, hs, Wp2, Up2, bp2,
                                               nullptr, Wd, bd, out);
}